// Round 3
// baseline (1071.074 us; speedup 1.0000x reference)
//
#include <hip/hip_runtime.h>

typedef unsigned int u32;
typedef unsigned long long u64;
typedef short short8 __attribute__((ext_vector_type(8)));
typedef unsigned short us8 __attribute__((ext_vector_type(8)));
typedef float v4f __attribute__((ext_vector_type(4)));

#define NTOK 65536
#define DIMS 256
#define NCODES 4096
#define MARGIN 0.02f
#define FLTMAX 3.402823466e38f

// ---------------- ws layout (bytes) ----------------
// zf/ef physical layout: [rowblk16][phys_k32 16][lane64=(r%16)+16*quad][8 bf16]
// phys tiles 0..7 = hi, 8..15 = lo. Logical K'=768 sweep re-reads hi.
#define ZF_OFF ((size_t)0)
#define ZF_BYTES ((size_t)NTOK * 512 * 2)  // 67108864
#define EF_OFF (ZF_OFF + ZF_BYTES)
#define EF_BYTES ((size_t)NCODES * 512 * 2)  // 4194304
#define EN_OFF (EF_OFF + EF_BYTES)
#define EN_BYTES ((size_t)NCODES * 4)
#define MK_OFF (EN_OFF + EN_BYTES)
#define MK_BYTES ((size_t)4 * NTOK * 8)  // u64 per (half, token)
#define MSV_OFF (MK_OFF + MK_BYTES)
#define MSV_BYTES ((size_t)4 * NTOK * 4)
#define CT_OFF (MSV_OFF + MSV_BYTES)
#define WL_OFF (CT_OFF + 256)
#define WL_BYTES ((size_t)NTOK * 4)
#define WS_REQ (WL_OFF + WL_BYTES)  // ~71.3 MB

__device__ __forceinline__ unsigned short f2bf(float f) {
  unsigned u = __float_as_uint(f);
  return (unsigned short)((u + 0x7FFFu + ((u >> 16) & 1u)) >> 16);
}
__device__ __forceinline__ float bf2f(unsigned short h) {
  return __uint_as_float(((unsigned)h) << 16);
}
__device__ __forceinline__ u32 umin32(u32 a, u32 b) { return a < b ? a : b; }
__device__ __forceinline__ u32 umax32(u32 a, u32 b) { return a > b ? a : b; }

__device__ __forceinline__ void async16(const unsigned short* g,
                                        unsigned short* l) {
  __builtin_amdgcn_global_load_lds(
      (const __attribute__((address_space(1))) unsigned int*)g,
      (__attribute__((address_space(3))) unsigned int*)l, 16, 0, 0);
}

// ---------------- split: fp32 -> bf16 hi/lo fragment layout (+opt norm) ----
// grid: rows/64 blocks x 256 thr. thread = (row-in-block = t>>2, quarter q=t&3)
__global__ __launch_bounds__(256) void split_kernel(
    const float* __restrict__ x, unsigned short* __restrict__ xf,
    float* __restrict__ norm_out, int* __restrict__ zero_me) {
  const int t = threadIdx.x;
  if (zero_me && blockIdx.x == 0 && t == 0) *zero_me = 0;
  const int row = blockIdx.x * 64 + (t >> 2);
  const int q = t & 3;
  const int rb = row >> 4, rl = row & 15;
  const float* src = x + (size_t)row * DIMS + q * 64;
  us8* dst = (us8*)xf;
  const size_t base = (size_t)rb * 1024 + rl;
  float s = 0.f;
#pragma unroll
  for (int o = 0; o < 8; ++o) {
    float4 f0 = ((const float4*)src)[o * 2];
    float4 f1 = ((const float4*)src)[o * 2 + 1];
    float v[8] = {f0.x, f0.y, f0.z, f0.w, f1.x, f1.y, f1.z, f1.w};
    us8 hi, lo;
#pragma unroll
    for (int i = 0; i < 8; ++i) {
      unsigned short h = f2bf(v[i]);
      hi[i] = h;
      lo[i] = f2bf(v[i] - bf2f(h));
      s += v[i] * v[i];
    }
    int k32l = q * 2 + (o >> 2);  // phys hi tile
    int qp = o & 3;
    dst[base + (size_t)k32l * 64 + 16 * qp] = hi;
    dst[base + (size_t)(k32l + 8) * 64 + 16 * qp] = lo;
  }
  if (norm_out) {
    s += __shfl_xor(s, 1, 64);
    s += __shfl_xor(s, 2, 64);
    if (q == 0) norm_out[row] = s + 1024.0f;  // biased ||e||^2 (argmin-safe)
  }
}

// ---------------- main: MFMA distance + packed-key 2-min ----------------
// 2048 blocks = 512 mb x 4 half. Block: 128 tokens x 1024 codes (8 n0i x 128).
// half = bid>>9 so blocks sharing an A-slice land on the same XCD (bid%8).
// K' logical = 768 ([z_hi|z_hi|z_lo] . [e_hi|e_lo|e_hi]) streamed as 12 steps
// of 2 k32-tiles from the deduped 512-wide physical layout.
__global__ __launch_bounds__(256, 3) void vq_mfma_kernel(
    const unsigned short* __restrict__ zf, const unsigned short* __restrict__ ef,
    const float* __restrict__ enorm, u64* __restrict__ mkey,
    u32* __restrict__ msv) {
  __shared__ short8 AS[1024];  // 16 chunks x 64 lanes (16 KB)
  __shared__ short8 BS[1024];
  __shared__ u64 red_key[2][128];
  __shared__ u32 red_sv[2][128];

  const int t = threadIdx.x;
  const int w = t >> 6, lane = t & 63;
  const int wm = w >> 1, wn = w & 1;
  const int quad = lane >> 4, l15 = lane & 15;
  const int bid = blockIdx.x;
  const int half = bid >> 9;
  const int mb = bid & 511;

  // staging bases: wave w stages chunks cc = w*4+q, q in [0,4):
  // rowblk ib = 2w + (q>>1), kk = q&1
  const unsigned short* baseA[4];
  const unsigned short* baseB[4];
#pragma unroll
  for (int q = 0; q < 4; ++q) {
    int ib = 2 * w + (q >> 1);
    baseA[q] = zf + ((size_t)(mb * 8 + ib) * 16) * 512 + lane * 8;
    baseB[q] = ef + ((size_t)(half * 64 + ib) * 16) * 512 + lane * 8;
  }

  u32 bv[16], sv[16];
#pragma unroll
  for (int s = 0; s < 16; ++s) {
    bv[s] = 0xFFFFFFFFu;
    sv[s] = 0xFFFFFFFFu;
  }

#pragma unroll 1
  for (int n0i = 0; n0i < 8; ++n0i) {
    float en[4];
#pragma unroll
    for (int j = 0; j < 4; ++j)
      en[j] = enorm[half * 1024 + n0i * 128 + wn * 64 + j * 16 + l15];

    v4f acc[4][4];
#pragma unroll
    for (int i = 0; i < 4; ++i)
#pragma unroll
      for (int j = 0; j < 4; ++j) acc[i][j] = (v4f){0.f, 0.f, 0.f, 0.f};

#pragma unroll
    for (int s = 0; s < 12; ++s) {
      const int pkz = (s < 4) ? 2 * s : 2 * s - 8;    // z: [hi|hi|lo]
      const int pke = (s < 8) ? 2 * s : 2 * s - 16;   // e: [hi|lo|hi]
      __syncthreads();
#pragma unroll
      for (int q = 0; q < 4; ++q) {
        async16(baseA[q] + (pkz + (q & 1)) * 512,
                (unsigned short*)&AS[(w * 4 + q) * 64]);
        async16(baseB[q] + (pke + (q & 1)) * 512,
                (unsigned short*)&BS[(w * 4 + q) * 64]);
      }
      __syncthreads();
#pragma unroll
      for (int ks = 0; ks < 2; ++ks) {
        short8 af[4], bf[4];
#pragma unroll
        for (int i = 0; i < 4; ++i)
          af[i] = AS[((wm * 4 + i) * 2 + ks) * 64 + lane];
#pragma unroll
        for (int j = 0; j < 4; ++j)
          bf[j] = BS[((wn * 4 + j) * 2 + ks) * 64 + lane];
#pragma unroll
        for (int i = 0; i < 4; ++i)
#pragma unroll
          for (int j = 0; j < 4; ++j)
            acc[i][j] = __builtin_amdgcn_mfma_f32_16x16x32_bf16(
                af[i], bf[j], acc[i][j], 0, 0, 0);
      }
    }

    // epilogue: key = bits(en - 2s) with 5-bit local id; 2-min tracking
#pragma unroll
    for (int j = 0; j < 4; ++j) {
      const u32 lid = (u32)(n0i * 4 + j);
      const float enj = en[j];
#pragma unroll
      for (int i = 0; i < 4; ++i)
#pragma unroll
        for (int r = 0; r < 4; ++r) {
          float d = fmaf(acc[i][j][r], -2.0f, enj);
          u32 key = (__float_as_uint(d) & 0xFFFFFFE0u) | lid;
          int s = i * 4 + r;
          u32 mx = umax32(bv[s], key);
          bv[s] = umin32(bv[s], key);
          sv[s] = umin32(sv[s], mx);
        }
    }

    // advance B bases to next 128-code tile
#pragma unroll
    for (int q = 0; q < 4; ++q) baseB[q] += 8 * 16 * 512;
  }

  // finalize: per-slot (key64 = val<<12 | code12, sval), butterfly over l15
#pragma unroll
  for (int s = 0; s < 16; ++s) {
    u32 val = bv[s] & 0xFFFFFFE0u;
    u32 lid = bv[s] & 31u;
    u32 code = half * 1024 + ((lid >> 2) << 7) + (wn << 6) + ((lid & 3) << 4) +
               l15;
    u64 k = ((u64)val << 12) | code;
    u32 svv = sv[s] & 0xFFFFFFE0u;
#pragma unroll
    for (int o = 1; o < 16; o <<= 1) {
      u32 klo = __shfl_xor((u32)k, o, 64);
      u32 khi = __shfl_xor((u32)(k >> 32), o, 64);
      u64 ok = ((u64)khi << 32) | klo;
      u32 osv = __shfl_xor(svv, o, 64);
      u64 mx = k > ok ? k : ok;
      k = k < ok ? k : ok;
      svv = umin32(umin32(svv, osv), (u32)(mx >> 12));
    }
    if (l15 == 0) {
      int row = wm * 64 + (s >> 2) * 16 + quad * 4 + (s & 3);
      red_key[wn][row] = k;
      red_sv[wn][row] = svv;
    }
  }
  __syncthreads();
  if (t < 128) {
    u64 k0 = red_key[0][t], k1 = red_key[1][t];
    u64 mx = k0 > k1 ? k0 : k1;
    u64 b = k0 < k1 ? k0 : k1;
    u32 s = umin32(umin32(red_sv[0][t], red_sv[1][t]), (u32)(mx >> 12));
    size_t tok = (size_t)mb * 128 + t;
    mkey[(size_t)half * NTOK + tok] = b;
    msv[(size_t)half * NTOK + tok] = s;
  }
}

// ---------------- merge: combine 4 halves, write idx, gather, flag -------
__global__ __launch_bounds__(256) void merge_kernel(
    const u64* __restrict__ mkey, const u32* __restrict__ msv,
    const float* __restrict__ emb, float* __restrict__ out_zq,
    float* __restrict__ out_idx, int* __restrict__ wl_count,
    int* __restrict__ wl) {
  __shared__ int sidx[128];
  const int t = threadIdx.x;
  const int tok0 = blockIdx.x * 128;
  if (t < 128) {
    int tok = tok0 + t;
    u64 b = mkey[tok];
    u32 s = msv[tok];
#pragma unroll
    for (int h = 1; h < 4; ++h) {
      u64 kh = mkey[(size_t)h * NTOK + tok];
      u32 sh = msv[(size_t)h * NTOK + tok];
      u64 mx = b > kh ? b : kh;
      b = b < kh ? b : kh;
      s = umin32(umin32(s, sh), (u32)(mx >> 12));
    }
    int code = (int)(b & 0xFFFu);
    out_idx[tok] = (float)code;
    sidx[t] = code;
    float gap = __uint_as_float(s) - __uint_as_float((u32)(b >> 12));
    if (gap < MARGIN) {
      int sl = atomicAdd(wl_count, 1);
      if (sl < NTOK) wl[sl] = tok;
    }
  }
  __syncthreads();
  {
    int row = t >> 1, hf = t & 1;
    int src = sidx[row];
    const float4* sp = (const float4*)(emb + (size_t)src * DIMS + hf * 128);
    float4* dp = (float4*)(out_zq + (size_t)(tok0 + row) * DIMS + hf * 128);
#pragma unroll
    for (int qd = 0; qd < 32; ++qd) dp[qd] = sp[qd];
  }
}

// ---------------- rescue: exact fp32 rescan, batched 4 tokens/block ------
__global__ __launch_bounds__(256) void rescue_kernel(
    const float* __restrict__ z, const float* __restrict__ emb,
    const float* __restrict__ enorm_b, const int* __restrict__ wl_count,
    const int* __restrict__ wl, float* __restrict__ out_zq,
    float* __restrict__ out_idx) {
  __shared__ __align__(16) float zr[4][256];
  __shared__ float rv[4][4];
  __shared__ int ri[4][4];
  __shared__ int sbest[4];
  const int t = threadIdx.x;
  const int wv = t >> 6, lane = t & 63;
  int n = *wl_count;
  if (n > NTOK) n = NTOK;
  for (int base = blockIdx.x * 4; base < n; base += 256 * 4) {
    int cnt = n - base;
    if (cnt > 4) cnt = 4;
    __syncthreads();
    for (int b2 = 0; b2 < cnt; ++b2)
      zr[b2][t] = z[(size_t)wl[base + b2] * DIMS + t];
    __syncthreads();
    float bvv[4] = {FLTMAX, FLTMAX, FLTMAX, FLTMAX};
    int bii[4] = {0, 0, 0, 0};
    for (int k = 0; k < 16; ++k) {
      int c = k * 256 + t;
      const float4* er = (const float4*)(emb + (size_t)c * DIMS);
      float d0 = 0.f, d1 = 0.f, d2 = 0.f, d3 = 0.f;
#pragma unroll 8
      for (int qd = 0; qd < 64; ++qd) {
        float4 ev = er[qd];
        float4 z0 = *(const float4*)&zr[0][qd * 4];
        float4 z1 = *(const float4*)&zr[1][qd * 4];
        float4 z2 = *(const float4*)&zr[2][qd * 4];
        float4 z3 = *(const float4*)&zr[3][qd * 4];
        d0 += ev.x * z0.x + ev.y * z0.y + ev.z * z0.z + ev.w * z0.w;
        d1 += ev.x * z1.x + ev.y * z1.y + ev.z * z1.z + ev.w * z1.w;
        d2 += ev.x * z2.x + ev.y * z2.y + ev.z * z2.z + ev.w * z2.w;
        d3 += ev.x * z3.x + ev.y * z3.y + ev.z * z3.z + ev.w * z3.w;
      }
      float en = enorm_b[c];
      float dd[4] = {en - 2.f * d0, en - 2.f * d1, en - 2.f * d2,
                     en - 2.f * d3};
#pragma unroll
      for (int b2 = 0; b2 < 4; ++b2)
        if (dd[b2] < bvv[b2]) {
          bvv[b2] = dd[b2];
          bii[b2] = c;
        }
    }
    // reduce: wave shuffle then cross-wave via LDS, first-index tie-break
#pragma unroll
    for (int b2 = 0; b2 < 4; ++b2) {
      float v = bvv[b2];
      int ix = bii[b2];
      for (int off = 32; off >= 1; off >>= 1) {
        float ov = __shfl_down(v, off, 64);
        int oi = __shfl_down(ix, off, 64);
        if (ov < v || (ov == v && oi < ix)) {
          v = ov;
          ix = oi;
        }
      }
      if (lane == 0) {
        rv[b2][wv] = v;
        ri[b2][wv] = ix;
      }
    }
    __syncthreads();
    if (t < cnt) {
      float v = rv[t][0];
      int ix = ri[t][0];
#pragma unroll
      for (int q = 1; q < 4; ++q) {
        float ov = rv[t][q];
        int oi = ri[t][q];
        if (ov < v || (ov == v && oi < ix)) {
          v = ov;
          ix = oi;
        }
      }
      out_idx[wl[base + t]] = (float)ix;
      sbest[t] = ix;
    }
    __syncthreads();
    for (int b2 = 0; b2 < cnt; ++b2)
      out_zq[(size_t)wl[base + b2] * DIMS + t] =
          emb[(size_t)sbest[b2] * DIMS + t];
  }
}

// ---------------- legacy fp32 fallback (ws too small) --------------------
__global__ void row_norm_kernel(const float* __restrict__ x,
                                float* __restrict__ out, int rows) {
  int wid = (blockIdx.x * blockDim.x + threadIdx.x) >> 6;
  int lane = threadIdx.x & 63;
  if (wid >= rows) return;
  const float* r = x + (size_t)wid * DIMS;
  float s = 0.f;
#pragma unroll
  for (int i = 0; i < DIMS / 64; ++i) {
    float v = r[lane + 64 * i];
    s += v * v;
  }
#pragma unroll
  for (int off = 32; off >= 1; off >>= 1) s += __shfl_down(s, off, 64);
  if (lane == 0) out[wid] = s;
}

__global__ __launch_bounds__(256) void vq_argmin_legacy(
    const float* __restrict__ z, const float* __restrict__ emb,
    const float* __restrict__ enorm, float* __restrict__ out_zq,
    float* __restrict__ out_idx) {
  __shared__ float As[32][128];
  __shared__ float Bs[32][128];
  __shared__ float red_v[128][17];
  __shared__ int red_i[128][17];
  const int t = threadIdx.x;
  const int tx = t & 15, ty = t >> 4;
  const int m0 = blockIdx.x * 128;
  float bestv[8];
  int besti[8];
#pragma unroll
  for (int i = 0; i < 8; ++i) {
    bestv[i] = FLTMAX;
    besti[i] = 0;
  }
  const int lrow = t >> 1;
  const int lhalf = t & 1;
  const float* zsrc_base = z + (size_t)(m0 + lrow) * DIMS + lhalf * 16;
  for (int n0 = 0; n0 < NCODES; n0 += 128) {
    float acc[8][8];
#pragma unroll
    for (int i = 0; i < 8; ++i)
#pragma unroll
      for (int j = 0; j < 8; ++j) acc[i][j] = 0.f;
    const float* esrc_base = emb + (size_t)(n0 + lrow) * DIMS + lhalf * 16;
    for (int k0 = 0; k0 < DIMS; k0 += 32) {
      __syncthreads();
      {
        const float4* s4 = (const float4*)(zsrc_base + k0);
        float4 v0 = s4[0], v1 = s4[1], v2 = s4[2], v3 = s4[3];
        int kb = lhalf * 16;
        float vv[16] = {v0.x, v0.y, v0.z, v0.w, v1.x, v1.y, v1.z, v1.w,
                        v2.x, v2.y, v2.z, v2.w, v3.x, v3.y, v3.z, v3.w};
#pragma unroll
        for (int q = 0; q < 16; ++q) As[kb + q][lrow] = vv[q];
      }
      {
        const float4* s4 = (const float4*)(esrc_base + k0);
        float4 v0 = s4[0], v1 = s4[1], v2 = s4[2], v3 = s4[3];
        int kb = lhalf * 16;
        float vv[16] = {v0.x, v0.y, v0.z, v0.w, v1.x, v1.y, v1.z, v1.w,
                        v2.x, v2.y, v2.z, v2.w, v3.x, v3.y, v3.z, v3.w};
#pragma unroll
        for (int q = 0; q < 16; ++q) Bs[kb + q][lrow] = vv[q];
      }
      __syncthreads();
#pragma unroll 8
      for (int k = 0; k < 32; ++k) {
        float4 a0 = *(const float4*)&As[k][ty * 4];
        float4 a1 = *(const float4*)&As[k][64 + ty * 4];
        float4 b0 = *(const float4*)&Bs[k][tx * 4];
        float4 b1 = *(const float4*)&Bs[k][64 + tx * 4];
        float a[8] = {a0.x, a0.y, a0.z, a0.w, a1.x, a1.y, a1.z, a1.w};
        float b[8] = {b0.x, b0.y, b0.z, b0.w, b1.x, b1.y, b1.z, b1.w};
#pragma unroll
        for (int i = 0; i < 8; ++i)
#pragma unroll
          for (int j = 0; j < 8; ++j) acc[i][j] += a[i] * b[j];
      }
    }
#pragma unroll
    for (int j = 0; j < 8; ++j) {
      int col = n0 + ((j < 4) ? (tx * 4 + j) : (64 + tx * 4 + (j - 4)));
      float en = enorm[col];
#pragma unroll
      for (int i = 0; i < 8; ++i) {
        int rowi = (i < 4) ? (ty * 4 + i) : (64 + ty * 4 + (i - 4));
        (void)rowi;
        float d = en - 2.0f * acc[i][j];
        if (d < bestv[i]) {
          bestv[i] = d;
          besti[i] = col;
        }
      }
    }
  }
#pragma unroll
  for (int i = 0; i < 8; ++i) {
    int rowi = (i < 4) ? (ty * 4 + i) : (64 + ty * 4 + (i - 4));
    red_v[rowi][tx] = bestv[i];
    red_i[rowi][tx] = besti[i];
  }
  __syncthreads();
  if (t < 128) {
    float bvv = red_v[t][0];
    int bii = red_i[t][0];
#pragma unroll
    for (int c = 1; c < 16; ++c) {
      float v = red_v[t][c];
      int ix = red_i[t][c];
      if (v < bvv || (v == bvv && ix < bii)) {
        bvv = v;
        bii = ix;
      }
    }
    out_idx[m0 + t] = (float)bii;
    red_i[t][16] = bii;
  }
  __syncthreads();
  {
    int grow = t >> 1, gh = t & 1;
    int src = red_i[grow][16];
    const float4* sp = (const float4*)(emb + (size_t)src * DIMS + gh * 128);
    float4* dp = (float4*)(out_zq + (size_t)(m0 + grow) * DIMS + gh * 128);
#pragma unroll
    for (int q = 0; q < 32; ++q) dp[q] = sp[q];
  }
}

extern "C" void kernel_launch(void* const* d_in, const int* in_sizes, int n_in,
                              void* d_out, int out_size, void* d_ws,
                              size_t ws_size, hipStream_t stream) {
  const float* z = (const float*)d_in[0];
  const float* emb = (const float*)d_in[1];
  float* out = (float*)d_out;
  float* out_zq = out;
  float* out_idx = out + (size_t)NTOK * DIMS;

  if (ws_size >= WS_REQ) {
    char* ws = (char*)d_ws;
    unsigned short* zf = (unsigned short*)(ws + ZF_OFF);
    unsigned short* ef = (unsigned short*)(ws + EF_OFF);
    float* enorm = (float*)(ws + EN_OFF);
    u64* mkey = (u64*)(ws + MK_OFF);
    u32* msv = (u32*)(ws + MSV_OFF);
    int* wl_count = (int*)(ws + CT_OFF);
    int* wl = (int*)(ws + WL_OFF);

    split_kernel<<<NTOK / 64, 256, 0, stream>>>(z, zf, nullptr, nullptr);
    split_kernel<<<NCODES / 64, 256, 0, stream>>>(emb, ef, enorm, wl_count);
    vq_mfma_kernel<<<2048, 256, 0, stream>>>(zf, ef, enorm, mkey, msv);
    merge_kernel<<<NTOK / 128, 256, 0, stream>>>(mkey, msv, emb, out_zq,
                                                 out_idx, wl_count, wl);
    rescue_kernel<<<256, 256, 0, stream>>>(z, emb, enorm, wl_count, wl, out_zq,
                                           out_idx);
  } else {
    float* enorm = (float*)d_ws;
    row_norm_kernel<<<NCODES / 4, 256, 0, stream>>>(emb, enorm, NCODES);
    vq_argmin_legacy<<<NTOK / 128, 256, 0, stream>>>(z, emb, enorm, out_zq,
                                                     out_idx);
  }
}